// Round 8
// baseline (457.955 us; speedup 1.0000x reference)
//
#include <hip/hip_runtime.h>
#include <math.h>

// Problem constants (from reference): B=32, I=2048, O=32, C=16, U=32
#define B_   32
#define I_   2048
#define O_   32
#define C_   16
#define U_   32
#define NCOL (O_ * U_)        // 1024 output columns (o,u)

// R10: the last untested cell of {occupancy x MLP}: 32 waves/CU WITH
// guaranteed MLP=4. R5/R9 showed the compiler sinks load batches to
// MLP=1 when register pressure is low (VGPR 32/36) -> latency-serialized
// 80-84us. R4 (16 waves/CU, MLP=4 via accidental 96-VGPR pressure) = 65us.
// Harness restore-copy reads ~3 TB/s at 32 waves/CU; our read cap ~2.2.
// Here: __launch_bounds__(512,8) (VGPR cap 64, 4 blk/CU, 32 waves/CU),
// acc[4]+wv[4] (~55 VGPR), and sched_barrier(0) between the 4-load batch
// and the FMA batch to pin all 4 loads in flight (compiler cannot sink).
#define TI   8                // i-values per block
#define OSPL 4                // o-split factor
#define OB_  (O_ / OSPL)      // 8 o-values per block
#define NIH  (I_ / TI)        // 256 i-chunks
#define NBLK (NIH * OSPL)     // 1024 blocks
#define SLICE (B_ * OB_ * U_) // 8192 floats per partial slice (32 KB)
#define XS   36               // x LDS stride (pad vs bank conflicts)

typedef float f32x4 __attribute__((ext_vector_type(4)));

// softmax over the singleton axis of b_log is identically 1 -> routing
// iterations are no-ops. Output = squash(sum_{i,c} x[b,i,c] * w[i,o,c,u]).

__global__ __launch_bounds__(512, 8) void caps_partial(const float* __restrict__ x,
                                                       const float* __restrict__ w,
                                                       float* __restrict__ ws) {
    __shared__ float xs[TI * C_ * XS];   // 18 KB: xs[rem*36 + b], rem = il*C + c
    const int tid = threadIdx.x;         // 0..511
    const int ih  = blockIdx.x & (NIH - 1);   // i-chunk (0..255)
    const int oq  = blockIdx.x >> 8;          // o-quarter (0..3)
    const int i0  = ih * TI;
    const int o0  = oq * OB_;

    // Stage x[:, i0:i0+TI, :] -> xs[rem*XS + b]. Global read coalesced.
    for (int k = tid; k < B_ * TI * C_; k += 512) {
        int b   = k >> 7;        // / (TI*C_) == 128
        int rem = k & 127;
        xs[rem * XS + b] = x[(size_t)b * (I_ * C_) + (size_t)i0 * C_ + rem];
    }
    __syncthreads();

    // thread decode: bq = batch-quad (4 b each), oo = o in quarter, u4 = u quad
    const int bq = tid >> 6;             // 0..7
    const int ct = tid & 63;
    const int oo = ct >> 3;              // 0..7
    const int u4 = (ct & 7) << 2;
    const float* wp = w + (size_t)i0 * (O_ * C_ * U_)
                    + (size_t)(o0 + oo) * (C_ * U_) + u4;

    float4 acc[4];                       // acc[m] : b = bq*4+m, u = u4..u4+3
#pragma unroll
    for (int m = 0; m < 4; ++m) acc[m] = make_float4(0.f, 0.f, 0.f, 0.f);

    for (int il = 0; il < TI; ++il) {
        const float* wpi = wp + (size_t)il * (O_ * C_ * U_);
        const float* xr  = &xs[(il * C_) * XS + bq * 4];
#pragma unroll
        for (int cc = 0; cc < C_; cc += 4) {
            f32x4 wv[4];
#pragma unroll
            for (int j = 0; j < 4; ++j)   // 4 loads issued back-to-back
                wv[j] = *(const f32x4*)(wpi + (cc + j) * U_);
            // Pin the load batch above the FMA batch: compiler cannot sink
            // loads to their uses (the R5/R9 MLP=1 failure mode).
            __builtin_amdgcn_sched_barrier(0);
#pragma unroll
            for (int j = 0; j < 4; ++j) {
                float4 xq = *(const float4*)(xr + (cc + j) * XS);  // broadcast
                acc[0].x = fmaf(xq.x, wv[j].x, acc[0].x);
                acc[0].y = fmaf(xq.x, wv[j].y, acc[0].y);
                acc[0].z = fmaf(xq.x, wv[j].z, acc[0].z);
                acc[0].w = fmaf(xq.x, wv[j].w, acc[0].w);
                acc[1].x = fmaf(xq.y, wv[j].x, acc[1].x);
                acc[1].y = fmaf(xq.y, wv[j].y, acc[1].y);
                acc[1].z = fmaf(xq.y, wv[j].z, acc[1].z);
                acc[1].w = fmaf(xq.y, wv[j].w, acc[1].w);
                acc[2].x = fmaf(xq.z, wv[j].x, acc[2].x);
                acc[2].y = fmaf(xq.z, wv[j].y, acc[2].y);
                acc[2].z = fmaf(xq.z, wv[j].z, acc[2].z);
                acc[2].w = fmaf(xq.z, wv[j].w, acc[2].w);
                acc[3].x = fmaf(xq.w, wv[j].x, acc[3].x);
                acc[3].y = fmaf(xq.w, wv[j].y, acc[3].y);
                acc[3].z = fmaf(xq.w, wv[j].z, acc[3].z);
                acc[3].w = fmaf(xq.w, wv[j].w, acc[3].w);
            }
        }
    }

    // ws[blk][b][oo][u]: wave covers contiguous 1 KB. slice = oq*256+ih.
    float* op = ws + (size_t)blockIdx.x * SLICE + (size_t)(bq * 4) * (OB_ * U_)
                + oo * U_ + u4;
#pragma unroll
    for (int m = 0; m < 4; ++m)
        *(float4*)(op + (size_t)m * (OB_ * U_)) = acc[m];
}

// Sum 256 i-chunk partials per element (2 threads/element over halves),
// then squash over u (32 consecutive e = one (b,o) group; shuffle reduce).
__global__ __launch_bounds__(256) void caps_reduce_squash(const float* __restrict__ ws,
                                                          float* __restrict__ out) {
    __shared__ float sh[128];
    const int tl = threadIdx.x & 127;
    const int ph = threadIdx.x >> 7;           // i-chunk half
    const int e  = blockIdx.x * 128 + tl;      // e in [0, 32768)
    const int b  = e >> 10;
    const int o  = (e >> 5) & 31;
    const int u  = e & 31;
    const int oq = o >> 3;
    const int oo = o & 7;
    const float* p = ws + ((size_t)oq * NIH + (size_t)ph * (NIH / 2)) * SLICE
                     + (size_t)b * (OB_ * U_) + oo * U_ + u;
    float s = 0.f;
#pragma unroll 16
    for (int i = 0; i < NIH / 2; ++i)
        s += p[(size_t)i * SLICE];
    if (ph) sh[tl] = s;
    __syncthreads();
    if (ph == 0) {
        s += sh[tl];
        float ss = s * s;
        ss += __shfl_xor(ss, 1);
        ss += __shfl_xor(ss, 2);
        ss += __shfl_xor(ss, 4);
        ss += __shfl_xor(ss, 8);
        ss += __shfl_xor(ss, 16);
        float n = sqrtf(ss);
        out[e] = s * n / (1.0f + ss);
    }
}

// ---------------- fallback (atomic path) if ws too small ----------------
#define FTI 4
__global__ __launch_bounds__(256, 2) void caps_main_atomic(const float* __restrict__ x,
                                                           const float* __restrict__ w,
                                                           float* __restrict__ out) {
    __shared__ float xs[FTI * C_ * 33];
    const int tid = threadIdx.x;
    const int i0 = blockIdx.x * FTI;
    for (int k = tid; k < B_ * FTI * C_; k += 256) {
        int b = k >> 6, rem = k & 63;
        xs[rem * 33 + b] = x[(size_t)b * (I_ * C_) + (size_t)i0 * C_ + rem];
    }
    __syncthreads();
    const int o = tid >> 3, u4 = (tid & 7) << 2;
    const float* wp = w + (size_t)i0 * (O_ * C_ * U_) + o * (C_ * U_) + u4;
    float4 acc[B_];
#pragma unroll
    for (int b = 0; b < B_; ++b) acc[b] = make_float4(0.f, 0.f, 0.f, 0.f);
    for (int il = 0; il < FTI; ++il) {
        const float* wpi = wp + (size_t)il * (O_ * C_ * U_);
        const float* xr = &xs[il * C_ * 33];
#pragma unroll
        for (int c = 0; c < C_; ++c) {
            float4 wv = *(const float4*)(wpi + c * U_);
            const float* xc = xr + c * 33;
#pragma unroll
            for (int b = 0; b < B_; ++b) {
                float xb = xc[b];
                acc[b].x = fmaf(xb, wv.x, acc[b].x);
                acc[b].y = fmaf(xb, wv.y, acc[b].y);
                acc[b].z = fmaf(xb, wv.z, acc[b].z);
                acc[b].w = fmaf(xb, wv.w, acc[b].w);
            }
        }
    }
    float* op = out + o * U_ + u4;
#pragma unroll
    for (int b = 0; b < B_; ++b) {
        float* p = op + (size_t)b * NCOL;
        atomicAdd(p + 0, acc[b].x);
        atomicAdd(p + 1, acc[b].y);
        atomicAdd(p + 2, acc[b].z);
        atomicAdd(p + 3, acc[b].w);
    }
}

__global__ void caps_squash_inplace(float* __restrict__ out) {
    int t = blockIdx.x * 256 + threadIdx.x;
    float s = out[t];
    float ss = s * s;
    ss += __shfl_xor(ss, 1);
    ss += __shfl_xor(ss, 2);
    ss += __shfl_xor(ss, 4);
    ss += __shfl_xor(ss, 8);
    ss += __shfl_xor(ss, 16);
    float n = sqrtf(ss);
    out[t] = s * n / (1.0f + ss);
}

extern "C" void kernel_launch(void* const* d_in, const int* in_sizes, int n_in,
                              void* d_out, int out_size, void* d_ws, size_t ws_size,
                              hipStream_t stream) {
    const float* x = (const float*)d_in[0];   // [B, I, C]
    const float* w = (const float*)d_in[1];   // [I, O, C, U]
    float* out = (float*)d_out;               // [B, O, 1, U] = 32768 floats

    const size_t need = (size_t)NBLK * SLICE * sizeof(float);   // 32 MB
    if (ws_size >= need) {
        float* ws = (float*)d_ws;
        caps_partial<<<NBLK, 512, 0, stream>>>(x, w, ws);
        caps_reduce_squash<<<(B_ * NCOL) / 128, 256, 0, stream>>>(ws, out);
    } else {
        hipMemsetAsync(out, 0, (size_t)(B_ * NCOL) * sizeof(float), stream);
        caps_main_atomic<<<I_ / FTI, 256, 0, stream>>>(x, w, out);
        caps_squash_inplace<<<(B_ * NCOL) / 256, 256, 0, stream>>>(out);
    }
}

// Round 9
// 321.190 us; speedup vs baseline: 1.4258x; 1.4258x over previous
//
#include <hip/hip_runtime.h>
#include <math.h>

// Problem constants (from reference): B=32, I=2048, O=32, C=16, U=32
#define B_   32
#define I_   2048
#define O_   32
#define C_   16
#define U_   32
#define NCOL (O_ * U_)        // 1024 output columns (o,u)

// R11 = R10 with ONE change: __launch_bounds__(512,8) -> (512,6).
// R10's (512,8) capped VGPR at 64; allocator emitted 32 + scratch spill
// (WRITE 641MB, partial 320us). But R10 proved (a) sched_barrier(0) does
// pin the wv[4] load batch (MLP held), (b) at 80% occupancy the chip
// sustains 3.3 TB/s -- above the ~2.2-2.5 TB/s cap of every clean
// 16-wave/CU kernel (R0/R4/R7/R8). (512,6): VGPR cap ~84, need ~60 ->
// no spill, 3 blk/CU = 24 waves/CU. Tests occupancy-scaling of the
// read path with MLP and the register file intact.
#define TI   8                // i-values per block
#define OSPL 4                // o-split factor
#define OB_  (O_ / OSPL)      // 8 o-values per block
#define NIH  (I_ / TI)        // 256 i-chunks
#define NBLK (NIH * OSPL)     // 1024 blocks
#define SLICE (B_ * OB_ * U_) // 8192 floats per partial slice (32 KB)
#define XS   36               // x LDS stride (pad vs bank conflicts)

typedef float f32x4 __attribute__((ext_vector_type(4)));

// softmax over the singleton axis of b_log is identically 1 -> routing
// iterations are no-ops. Output = squash(sum_{i,c} x[b,i,c] * w[i,o,c,u]).

__global__ __launch_bounds__(512, 6) void caps_partial(const float* __restrict__ x,
                                                       const float* __restrict__ w,
                                                       float* __restrict__ ws) {
    __shared__ float xs[TI * C_ * XS];   // 18 KB: xs[rem*36 + b], rem = il*C + c
    const int tid = threadIdx.x;         // 0..511
    const int ih  = blockIdx.x & (NIH - 1);   // i-chunk (0..255)
    const int oq  = blockIdx.x >> 8;          // o-quarter (0..3)
    const int i0  = ih * TI;
    const int o0  = oq * OB_;

    // Stage x[:, i0:i0+TI, :] -> xs[rem*XS + b]. Global read coalesced.
    for (int k = tid; k < B_ * TI * C_; k += 512) {
        int b   = k >> 7;        // / (TI*C_) == 128
        int rem = k & 127;
        xs[rem * XS + b] = x[(size_t)b * (I_ * C_) + (size_t)i0 * C_ + rem];
    }
    __syncthreads();

    // thread decode: bq = batch-quad (4 b each), oo = o in quarter, u4 = u quad
    const int bq = tid >> 6;             // 0..7
    const int ct = tid & 63;
    const int oo = ct >> 3;              // 0..7
    const int u4 = (ct & 7) << 2;
    const float* wp = w + (size_t)i0 * (O_ * C_ * U_)
                    + (size_t)(o0 + oo) * (C_ * U_) + u4;

    float4 acc[4];                       // acc[m] : b = bq*4+m, u = u4..u4+3
#pragma unroll
    for (int m = 0; m < 4; ++m) acc[m] = make_float4(0.f, 0.f, 0.f, 0.f);

    for (int il = 0; il < TI; ++il) {
        const float* wpi = wp + (size_t)il * (O_ * C_ * U_);
        const float* xr  = &xs[(il * C_) * XS + bq * 4];
#pragma unroll
        for (int cc = 0; cc < C_; cc += 4) {
            f32x4 wv[4];
#pragma unroll
            for (int j = 0; j < 4; ++j)   // 4 loads issued back-to-back
                wv[j] = *(const f32x4*)(wpi + (cc + j) * U_);
            // Pin the load batch above the FMA batch (R5/R9 MLP=1 guard).
            __builtin_amdgcn_sched_barrier(0);
#pragma unroll
            for (int j = 0; j < 4; ++j) {
                float4 xq = *(const float4*)(xr + (cc + j) * XS);  // broadcast
                acc[0].x = fmaf(xq.x, wv[j].x, acc[0].x);
                acc[0].y = fmaf(xq.x, wv[j].y, acc[0].y);
                acc[0].z = fmaf(xq.x, wv[j].z, acc[0].z);
                acc[0].w = fmaf(xq.x, wv[j].w, acc[0].w);
                acc[1].x = fmaf(xq.y, wv[j].x, acc[1].x);
                acc[1].y = fmaf(xq.y, wv[j].y, acc[1].y);
                acc[1].z = fmaf(xq.y, wv[j].z, acc[1].z);
                acc[1].w = fmaf(xq.y, wv[j].w, acc[1].w);
                acc[2].x = fmaf(xq.z, wv[j].x, acc[2].x);
                acc[2].y = fmaf(xq.z, wv[j].y, acc[2].y);
                acc[2].z = fmaf(xq.z, wv[j].z, acc[2].z);
                acc[2].w = fmaf(xq.z, wv[j].w, acc[2].w);
                acc[3].x = fmaf(xq.w, wv[j].x, acc[3].x);
                acc[3].y = fmaf(xq.w, wv[j].y, acc[3].y);
                acc[3].z = fmaf(xq.w, wv[j].z, acc[3].z);
                acc[3].w = fmaf(xq.w, wv[j].w, acc[3].w);
            }
        }
    }

    // ws[blk][b][oo][u]: wave covers contiguous 1 KB. slice = oq*256+ih.
    float* op = ws + (size_t)blockIdx.x * SLICE + (size_t)(bq * 4) * (OB_ * U_)
                + oo * U_ + u4;
#pragma unroll
    for (int m = 0; m < 4; ++m)
        *(float4*)(op + (size_t)m * (OB_ * U_)) = acc[m];
}

// Sum 256 i-chunk partials per element (2 threads/element over halves),
// then squash over u (32 consecutive e = one (b,o) group; shuffle reduce).
__global__ __launch_bounds__(256) void caps_reduce_squash(const float* __restrict__ ws,
                                                          float* __restrict__ out) {
    __shared__ float sh[128];
    const int tl = threadIdx.x & 127;
    const int ph = threadIdx.x >> 7;           // i-chunk half
    const int e  = blockIdx.x * 128 + tl;      // e in [0, 32768)
    const int b  = e >> 10;
    const int o  = (e >> 5) & 31;
    const int u  = e & 31;
    const int oq = o >> 3;
    const int oo = o & 7;
    const float* p = ws + ((size_t)oq * NIH + (size_t)ph * (NIH / 2)) * SLICE
                     + (size_t)b * (OB_ * U_) + oo * U_ + u;
    float s = 0.f;
#pragma unroll 16
    for (int i = 0; i < NIH / 2; ++i)
        s += p[(size_t)i * SLICE];
    if (ph) sh[tl] = s;
    __syncthreads();
    if (ph == 0) {
        s += sh[tl];
        float ss = s * s;
        ss += __shfl_xor(ss, 1);
        ss += __shfl_xor(ss, 2);
        ss += __shfl_xor(ss, 4);
        ss += __shfl_xor(ss, 8);
        ss += __shfl_xor(ss, 16);
        float n = sqrtf(ss);
        out[e] = s * n / (1.0f + ss);
    }
}

// ---------------- fallback (atomic path) if ws too small ----------------
#define FTI 4
__global__ __launch_bounds__(256, 2) void caps_main_atomic(const float* __restrict__ x,
                                                           const float* __restrict__ w,
                                                           float* __restrict__ out) {
    __shared__ float xs[FTI * C_ * 33];
    const int tid = threadIdx.x;
    const int i0 = blockIdx.x * FTI;
    for (int k = tid; k < B_ * FTI * C_; k += 256) {
        int b = k >> 6, rem = k & 63;
        xs[rem * 33 + b] = x[(size_t)b * (I_ * C_) + (size_t)i0 * C_ + rem];
    }
    __syncthreads();
    const int o = tid >> 3, u4 = (tid & 7) << 2;
    const float* wp = w + (size_t)i0 * (O_ * C_ * U_) + o * (C_ * U_) + u4;
    float4 acc[B_];
#pragma unroll
    for (int b = 0; b < B_; ++b) acc[b] = make_float4(0.f, 0.f, 0.f, 0.f);
    for (int il = 0; il < FTI; ++il) {
        const float* wpi = wp + (size_t)il * (O_ * C_ * U_);
        const float* xr = &xs[il * C_ * 33];
#pragma unroll
        for (int c = 0; c < C_; ++c) {
            float4 wv = *(const float4*)(wpi + c * U_);
            const float* xc = xr + c * 33;
#pragma unroll
            for (int b = 0; b < B_; ++b) {
                float xb = xc[b];
                acc[b].x = fmaf(xb, wv.x, acc[b].x);
                acc[b].y = fmaf(xb, wv.y, acc[b].y);
                acc[b].z = fmaf(xb, wv.z, acc[b].z);
                acc[b].w = fmaf(xb, wv.w, acc[b].w);
            }
        }
    }
    float* op = out + o * U_ + u4;
#pragma unroll
    for (int b = 0; b < B_; ++b) {
        float* p = op + (size_t)b * NCOL;
        atomicAdd(p + 0, acc[b].x);
        atomicAdd(p + 1, acc[b].y);
        atomicAdd(p + 2, acc[b].z);
        atomicAdd(p + 3, acc[b].w);
    }
}

__global__ void caps_squash_inplace(float* __restrict__ out) {
    int t = blockIdx.x * 256 + threadIdx.x;
    float s = out[t];
    float ss = s * s;
    ss += __shfl_xor(ss, 1);
    ss += __shfl_xor(ss, 2);
    ss += __shfl_xor(ss, 4);
    ss += __shfl_xor(ss, 8);
    ss += __shfl_xor(ss, 16);
    float n = sqrtf(ss);
    out[t] = s * n / (1.0f + ss);
}

extern "C" void kernel_launch(void* const* d_in, const int* in_sizes, int n_in,
                              void* d_out, int out_size, void* d_ws, size_t ws_size,
                              hipStream_t stream) {
    const float* x = (const float*)d_in[0];   // [B, I, C]
    const float* w = (const float*)d_in[1];   // [I, O, C, U]
    float* out = (float*)d_out;               // [B, O, 1, U] = 32768 floats

    const size_t need = (size_t)NBLK * SLICE * sizeof(float);   // 32 MB
    if (ws_size >= need) {
        float* ws = (float*)d_ws;
        caps_partial<<<NBLK, 512, 0, stream>>>(x, w, ws);
        caps_reduce_squash<<<(B_ * NCOL) / 128, 256, 0, stream>>>(ws, out);
    } else {
        hipMemsetAsync(out, 0, (size_t)(B_ * NCOL) * sizeof(float), stream);
        caps_main_atomic<<<I_ / FTI, 256, 0, stream>>>(x, w, out);
        caps_squash_inplace<<<(B_ * NCOL) / 256, 256, 0, stream>>>(out);
    }
}

// Round 10
// 219.189 us; speedup vs baseline: 2.0893x; 1.4654x over previous
//
#include <hip/hip_runtime.h>
#include <math.h>

// Problem constants (from reference): B=32, I=2048, O=32, C=16, U=32
#define B_   32
#define I_   2048
#define O_   32
#define C_   16
#define U_   32
#define NCOL (O_ * U_)        // 1024 output columns (o,u)

// R12: launch-bounds decoder from R10/R11 spills: THIS hipcc treats the
// 2nd __launch_bounds__ arg as min BLOCKS/CU (CUDA semantics):
//   (512,8) -> 64 waves/CU -> VGPR cap 32 (R10, spill, 320us)
//   (512,6) -> 48 waves/CU -> VGPR cap 40 (R11, spill, 180us)
// So (512,4) -> 32 waves/CU (full) -> VGPR cap 64 >= ~55 working set.
// R12 = R9's (512,4) bound [VGPR 36, no spill, but MLP=1 -> 80us] +
// R10's sched_barrier(0) MLP fence [held, but reg-starved]. First config
// with all three: 32 waves/CU, MLP=4 pinned, no spill.
// Occupancy->BW ledger: 16w=2.2-2.5 TB/s, 48w=2.77 (spilling!), 64w=3.3.
#define TI   8                // i-values per block
#define OSPL 4                // o-split factor
#define OB_  (O_ / OSPL)      // 8 o-values per block
#define NIH  (I_ / TI)        // 256 i-chunks
#define NBLK (NIH * OSPL)     // 1024 blocks = exactly 4/CU
#define SLICE (B_ * OB_ * U_) // 8192 floats per partial slice (32 KB)
#define XS   36               // x LDS stride (pad vs bank conflicts)

typedef float f32x4 __attribute__((ext_vector_type(4)));

// softmax over the singleton axis of b_log is identically 1 -> routing
// iterations are no-ops. Output = squash(sum_{i,c} x[b,i,c] * w[i,o,c,u]).

__global__ __launch_bounds__(512, 4) void caps_partial(const float* __restrict__ x,
                                                       const float* __restrict__ w,
                                                       float* __restrict__ ws) {
    __shared__ float xs[TI * C_ * XS];   // 18 KB: xs[rem*36 + b], rem = il*C + c
    const int tid = threadIdx.x;         // 0..511
    const int ih  = blockIdx.x & (NIH - 1);   // i-chunk (0..255)
    const int oq  = blockIdx.x >> 8;          // o-quarter (0..3)
    const int i0  = ih * TI;
    const int o0  = oq * OB_;

    // Stage x[:, i0:i0+TI, :] -> xs[rem*XS + b]. Global read coalesced.
    for (int k = tid; k < B_ * TI * C_; k += 512) {
        int b   = k >> 7;        // / (TI*C_) == 128
        int rem = k & 127;
        xs[rem * XS + b] = x[(size_t)b * (I_ * C_) + (size_t)i0 * C_ + rem];
    }
    __syncthreads();

    // thread decode: bq = batch-quad (4 b each), oo = o in quarter, u4 = u quad
    const int bq = tid >> 6;             // 0..7
    const int ct = tid & 63;
    const int oo = ct >> 3;              // 0..7
    const int u4 = (ct & 7) << 2;
    const float* wp = w + (size_t)i0 * (O_ * C_ * U_)
                    + (size_t)(o0 + oo) * (C_ * U_) + u4;

    float4 acc[4];                       // acc[m] : b = bq*4+m, u = u4..u4+3
#pragma unroll
    for (int m = 0; m < 4; ++m) acc[m] = make_float4(0.f, 0.f, 0.f, 0.f);

    for (int il = 0; il < TI; ++il) {
        const float* wpi = wp + (size_t)il * (O_ * C_ * U_);
        const float* xr  = &xs[(il * C_) * XS + bq * 4];
#pragma unroll
        for (int cc = 0; cc < C_; cc += 4) {
            f32x4 wv[4];
#pragma unroll
            for (int j = 0; j < 4; ++j)   // 4 loads issued back-to-back
                wv[j] = *(const f32x4*)(wpi + (cc + j) * U_);
            // Pin the load batch above the FMA batch (R5/R9 MLP=1 guard).
            __builtin_amdgcn_sched_barrier(0);
#pragma unroll
            for (int j = 0; j < 4; ++j) {
                float4 xq = *(const float4*)(xr + (cc + j) * XS);  // broadcast
                acc[0].x = fmaf(xq.x, wv[j].x, acc[0].x);
                acc[0].y = fmaf(xq.x, wv[j].y, acc[0].y);
                acc[0].z = fmaf(xq.x, wv[j].z, acc[0].z);
                acc[0].w = fmaf(xq.x, wv[j].w, acc[0].w);
                acc[1].x = fmaf(xq.y, wv[j].x, acc[1].x);
                acc[1].y = fmaf(xq.y, wv[j].y, acc[1].y);
                acc[1].z = fmaf(xq.y, wv[j].z, acc[1].z);
                acc[1].w = fmaf(xq.y, wv[j].w, acc[1].w);
                acc[2].x = fmaf(xq.z, wv[j].x, acc[2].x);
                acc[2].y = fmaf(xq.z, wv[j].y, acc[2].y);
                acc[2].z = fmaf(xq.z, wv[j].z, acc[2].z);
                acc[2].w = fmaf(xq.z, wv[j].w, acc[2].w);
                acc[3].x = fmaf(xq.w, wv[j].x, acc[3].x);
                acc[3].y = fmaf(xq.w, wv[j].y, acc[3].y);
                acc[3].z = fmaf(xq.w, wv[j].z, acc[3].z);
                acc[3].w = fmaf(xq.w, wv[j].w, acc[3].w);
            }
        }
    }

    // ws[blk][b][oo][u]: wave covers contiguous 1 KB. slice = oq*256+ih.
    float* op = ws + (size_t)blockIdx.x * SLICE + (size_t)(bq * 4) * (OB_ * U_)
                + oo * U_ + u4;
#pragma unroll
    for (int m = 0; m < 4; ++m)
        *(float4*)(op + (size_t)m * (OB_ * U_)) = acc[m];
}

// Sum 256 i-chunk partials per element (2 threads/element over halves),
// then squash over u (32 consecutive e = one (b,o) group; shuffle reduce).
__global__ __launch_bounds__(256) void caps_reduce_squash(const float* __restrict__ ws,
                                                          float* __restrict__ out) {
    __shared__ float sh[128];
    const int tl = threadIdx.x & 127;
    const int ph = threadIdx.x >> 7;           // i-chunk half
    const int e  = blockIdx.x * 128 + tl;      // e in [0, 32768)
    const int b  = e >> 10;
    const int o  = (e >> 5) & 31;
    const int u  = e & 31;
    const int oq = o >> 3;
    const int oo = o & 7;
    const float* p = ws + ((size_t)oq * NIH + (size_t)ph * (NIH / 2)) * SLICE
                     + (size_t)b * (OB_ * U_) + oo * U_ + u;
    float s = 0.f;
#pragma unroll 16
    for (int i = 0; i < NIH / 2; ++i)
        s += p[(size_t)i * SLICE];
    if (ph) sh[tl] = s;
    __syncthreads();
    if (ph == 0) {
        s += sh[tl];
        float ss = s * s;
        ss += __shfl_xor(ss, 1);
        ss += __shfl_xor(ss, 2);
        ss += __shfl_xor(ss, 4);
        ss += __shfl_xor(ss, 8);
        ss += __shfl_xor(ss, 16);
        float n = sqrtf(ss);
        out[e] = s * n / (1.0f + ss);
    }
}

// ---------------- fallback (atomic path) if ws too small ----------------
#define FTI 4
__global__ __launch_bounds__(256, 2) void caps_main_atomic(const float* __restrict__ x,
                                                           const float* __restrict__ w,
                                                           float* __restrict__ out) {
    __shared__ float xs[FTI * C_ * 33];
    const int tid = threadIdx.x;
    const int i0 = blockIdx.x * FTI;
    for (int k = tid; k < B_ * FTI * C_; k += 256) {
        int b = k >> 6, rem = k & 63;
        xs[rem * 33 + b] = x[(size_t)b * (I_ * C_) + (size_t)i0 * C_ + rem];
    }
    __syncthreads();
    const int o = tid >> 3, u4 = (tid & 7) << 2;
    const float* wp = w + (size_t)i0 * (O_ * C_ * U_) + o * (C_ * U_) + u4;
    float4 acc[B_];
#pragma unroll
    for (int b = 0; b < B_; ++b) acc[b] = make_float4(0.f, 0.f, 0.f, 0.f);
    for (int il = 0; il < FTI; ++il) {
        const float* wpi = wp + (size_t)il * (O_ * C_ * U_);
        const float* xr = &xs[il * C_ * 33];
#pragma unroll
        for (int c = 0; c < C_; ++c) {
            float4 wv = *(const float4*)(wpi + c * U_);
            const float* xc = xr + c * 33;
#pragma unroll
            for (int b = 0; b < B_; ++b) {
                float xb = xc[b];
                acc[b].x = fmaf(xb, wv.x, acc[b].x);
                acc[b].y = fmaf(xb, wv.y, acc[b].y);
                acc[b].z = fmaf(xb, wv.z, acc[b].z);
                acc[b].w = fmaf(xb, wv.w, acc[b].w);
            }
        }
    }
    float* op = out + o * U_ + u4;
#pragma unroll
    for (int b = 0; b < B_; ++b) {
        float* p = op + (size_t)b * NCOL;
        atomicAdd(p + 0, acc[b].x);
        atomicAdd(p + 1, acc[b].y);
        atomicAdd(p + 2, acc[b].z);
        atomicAdd(p + 3, acc[b].w);
    }
}

__global__ void caps_squash_inplace(float* __restrict__ out) {
    int t = blockIdx.x * 256 + threadIdx.x;
    float s = out[t];
    float ss = s * s;
    ss += __shfl_xor(ss, 1);
    ss += __shfl_xor(ss, 2);
    ss += __shfl_xor(ss, 4);
    ss += __shfl_xor(ss, 8);
    ss += __shfl_xor(ss, 16);
    float n = sqrtf(ss);
    out[t] = s * n / (1.0f + ss);
}

extern "C" void kernel_launch(void* const* d_in, const int* in_sizes, int n_in,
                              void* d_out, int out_size, void* d_ws, size_t ws_size,
                              hipStream_t stream) {
    const float* x = (const float*)d_in[0];   // [B, I, C]
    const float* w = (const float*)d_in[1];   // [I, O, C, U]
    float* out = (float*)d_out;               // [B, O, 1, U] = 32768 floats

    const size_t need = (size_t)NBLK * SLICE * sizeof(float);   // 32 MB
    if (ws_size >= need) {
        float* ws = (float*)d_ws;
        caps_partial<<<NBLK, 512, 0, stream>>>(x, w, ws);
        caps_reduce_squash<<<(B_ * NCOL) / 128, 256, 0, stream>>>(ws, out);
    } else {
        hipMemsetAsync(out, 0, (size_t)(B_ * NCOL) * sizeof(float), stream);
        caps_main_atomic<<<I_ / FTI, 256, 0, stream>>>(x, w, out);
        caps_squash_inplace<<<(B_ * NCOL) / 256, 256, 0, stream>>>(out);
    }
}